// Round 5
// baseline (1077.039 us; speedup 1.0000x reference)
//
#include <hip/hip_runtime.h>

#define N_NODES 100000
#define N1 (N_NODES + 1)
#define N_EDGES 3200000
#define N_GRAPHS 1000
#define IN_DIM 10
#define HIDDEN 64
#define NQUADS (N_NODES / 4)

#define NRANGES 8
#define RANGE_SIZE ((N_NODES + NRANGES - 1) / NRANGES)  // 12500
#define CHUNK_EDGES 4096

#define SLICE (N1 * 8)          // floats per 8-dim slice table
#define GNB ((N_NODES + 3) / 4) // gather blocks per pass (4 nodes/block)

// ---------------- degree histogram ----------------
__global__ void k_deg(const int* __restrict__ col, int* __restrict__ deg) {
    int e = blockIdx.x * blockDim.x + threadIdx.x;
    if (e < N_EDGES) atomicAdd(&deg[col[e]], 1);
}

// ---------------- hierarchical exclusive scan (offsets) ----------------
__global__ __launch_bounds__(1024) void k_scan_block(const int* __restrict__ deg,
                                                     int* __restrict__ offs,
                                                     int* __restrict__ bsums) {
    __shared__ int s[1024];
    int t = threadIdx.x;
    int i = blockIdx.x * 1024 + t;
    int v = (i < N_NODES) ? deg[i] : 0;
    s[t] = v;
    __syncthreads();
    for (int d = 1; d < 1024; d <<= 1) {
        int x = (t >= d) ? s[t - d] : 0;
        __syncthreads();
        s[t] += x;
        __syncthreads();
    }
    if (i < N_NODES) offs[i] = s[t] - v;
    if (t == 1023) bsums[blockIdx.x] = s[t];
}

__global__ __launch_bounds__(128) void k_scan_top(int* __restrict__ bsums, int nb) {
    __shared__ int s[128];
    int t = threadIdx.x;
    int v = (t < nb) ? bsums[t] : 0;
    s[t] = v;
    __syncthreads();
    for (int d = 1; d < 128; d <<= 1) {
        int x = (t >= d) ? s[t - d] : 0;
        __syncthreads();
        s[t] += x;
        __syncthreads();
    }
    if (t < nb) bsums[t] = s[t] - v;
}

__global__ __launch_bounds__(1024) void k_scan_add(int* __restrict__ offs,
                                                   const int* __restrict__ bsums) {
    int i = blockIdx.x * 1024 + threadIdx.x;
    if (i < N_NODES) offs[i] += bsums[blockIdx.x];
}

// ---------------- dinv ----------------
__global__ void k_dinv(const int* __restrict__ deg, float* __restrict__ dinv) {
    int n = blockIdx.x * blockDim.x + threadIdx.x;
    if (n < N_NODES) {
        int d = deg[n];
        dinv[n] = (d > 0) ? rsqrtf((float)d) : 0.f;
    }
}

// ---------------- CSR fill, XCD-range-partitioned (R2, kept) ----------------
__global__ __launch_bounds__(256) void k_fill(const int* __restrict__ row,
                                              const int* __restrict__ col,
                                              const int* __restrict__ offs,
                                              int* __restrict__ cursor,
                                              int* __restrict__ csr_src) {
    int range = blockIdx.x & (NRANGES - 1);
    int chunk = blockIdx.x >> 3;
    int lo = range * RANGE_SIZE;
    int hi = lo + RANGE_SIZE;
    int base = chunk * CHUNK_EDGES + threadIdx.x;
#pragma unroll
    for (int k = 0; k < CHUNK_EDGES / 256; ++k) {
        int e = base + k * 256;
        if (e < N_EDGES) {
            int c = col[e];
            int r = row[e];
            if (c >= lo && c < hi) {
                int p = atomicAdd(&cursor[c], 1);
                csr_src[offs[c] + p] = r;
            }
        }
    }
}

// ---------------- prescale x into 2 slice tables [2][N1][8] ----------------
__global__ void k_prex(const float* __restrict__ x, const float* __restrict__ dinv,
                       float* __restrict__ xsAB) {
    int i = blockIdx.x * blockDim.x + threadIdx.x;
    if (i >= N1 * 16) return;
    int n = i >> 4, d = i & 15;
    float v = 0.f;
    if (n < N_NODES && d < IN_DIM) v = x[n * IN_DIM + d] * dinv[n];
    xsAB[(d >> 3) * SLICE + n * 8 + (d & 7)] = v;
}

// ---------------- zero the gather-sink rows of the h slice table ----------------
__global__ void k_zerosink(float* __restrict__ hslc) {
    int t = threadIdx.x;  // 64
    hslc[(t >> 3) * SLICE + N_NODES * 8 + (t & 7)] = 0.f;
}

// ---------------- graph boundaries (batch is sorted) ----------------
__global__ void k_bounds(const int* __restrict__ batch, int* __restrict__ gmin,
                         int* __restrict__ gmax) {
    int n = blockIdx.x * blockDim.x + threadIdx.x;
    if (n < N_NODES) {
        int g = batch[n];
        atomicMin(&gmin[g], n);
        atomicMax(&gmax[g], n + 1);
    }
}

// ============ sliced gather: pass p sums 8-dim slice over each node's edges ============
// grid.x = NPASS*GNB, pass-major: blocks of pass p dispatch (roughly) before p+1,
// keeping the 3.2MB slice L2-resident per XCD. csr via NT loads (no L2 pollution).
// wave = 1 node; 64 lanes = 8 edge-subslots x 8 dims; sink row N_NODES = zeros.
__global__ __launch_bounds__(256) void k_gather8(const float* __restrict__ tab0,
                                                 const int* __restrict__ offs,
                                                 const int* __restrict__ deg,
                                                 const int* __restrict__ csr,
                                                 float* __restrict__ out0) {
    int pass = blockIdx.x / GNB;
    int nb = blockIdx.x - pass * GNB;
    const float* tab = tab0 + pass * SLICE;
    float* outp = out0 + pass * SLICE;
    int lane = threadIdx.x & 63;
    int eg = lane >> 3, f = lane & 7;
    int n = nb * 4 + (threadIdx.x >> 6);
    if (n >= N_NODES) return;
    int start = offs[n], dn = deg[n];
    float acc = 0.f;
    for (int base = 0; base < dn; base += 64) {
        int raw = __builtin_nontemporal_load(&csr[start + base + lane]);
        int idx = (base + lane < dn) ? raw : N_NODES;
        float v[8];
#pragma unroll
        for (int t = 0; t < 8; ++t) {
            int sj = __shfl(idx, t * 8 + eg);
            v[t] = tab[sj * 8 + f];
        }
#pragma unroll
        for (int t = 0; t < 8; ++t) acc += v[t];
    }
    acc += __shfl_xor(acc, 8);
    acc += __shfl_xor(acc, 16);
    acc += __shfl_xor(acc, 32);
    if (lane < 8) outp[n * 8 + lane] = acc;
}

// ============ dense 1: agg(16 padded dims) @ W1 + b1, relu, *dinv -> h1slc ============
__global__ __launch_bounds__(256) void k_dense1(const float* __restrict__ agg, // [2][N1][8]
                                                const float* __restrict__ dinv,
                                                const float* __restrict__ W1,
                                                const float* __restrict__ b1,
                                                float* __restrict__ h1slc) {  // [8][N1][8]
    int lane = threadIdx.x & 63;
    int f16 = lane & 15;
    float W1reg[16];
#pragma unroll
    for (int k = 0; k < 16; ++k) W1reg[k] = (k < IN_DIM) ? W1[k * HIDDEN + lane] : 0.f;
    float b1reg = b1[lane];
    int so = (lane >> 3) * SLICE + (lane & 7);
    int ain = (f16 >> 3) * SLICE + (f16 & 7);
    int wid = (blockIdx.x * 256 + threadIdx.x) >> 6;
    int nwaves = gridDim.x * 4;
    for (int quad = wid; quad < NQUADS; quad += nwaves) {
        int n = quad * 4 + (lane >> 4);
        float a = agg[ain + n * 8] * dinv[n];
#pragma unroll
        for (int g = 0; g < 4; ++g) {
            float acc = b1reg;
#pragma unroll
            for (int k = 0; k < 16; ++k) acc += __shfl(a, g * 16 + k) * W1reg[k];
            int ng = quad * 4 + g;
            h1slc[so + ng * 8] = fmaxf(acc, 0.f) * dinv[ng];
        }
    }
}

// ============ dense 2: agg(64) @ W + b, relu, *dinv -> out slice table ============
__global__ __launch_bounds__(256) void k_dense2(const float* __restrict__ agg, // [8][N1][8]
                                                const float* __restrict__ dinv,
                                                const float* __restrict__ W,
                                                const float* __restrict__ b,
                                                float* __restrict__ outslc) {  // [8][N1][8]
    __shared__ float4 sW4[HIDDEN][16];
    for (int i = threadIdx.x; i < HIDDEN * 16; i += 256) {
        int k = i >> 4, ff = i & 15;
        sW4[k][ff] = *(const float4*)&W[k * HIDDEN + ff * 4];
    }
    __syncthreads();
    int lane = threadIdx.x & 63;
    int f = lane & 15, gbase = lane & 48;
    float4 b4 = *(const float4*)&b[f * 4];
    int aoff = (f >> 1) * SLICE + (f & 1) * 4;  // float4 at dims f*4..f*4+3
    int wid = (blockIdx.x * 256 + threadIdx.x) >> 6;
    int nwaves = gridDim.x * 4;
    for (int quad = wid; quad < NQUADS; quad += nwaves) {
        int n = quad * 4 + (lane >> 4);
        float di = dinv[n];
        float4 acc = *(const float4*)&agg[aoff + n * 8];
        acc.x *= di; acc.y *= di; acc.z *= di; acc.w *= di;
        float4 out = b4;
#pragma unroll
        for (int k = 0; k < HIDDEN; ++k) {
            float srcval = (k & 3) == 0 ? acc.x : (k & 3) == 1 ? acc.y : (k & 3) == 2 ? acc.z : acc.w;
            float ak = __shfl(srcval, gbase + (k >> 2));
            float4 w4 = sW4[k][f];
            out.x += ak * w4.x; out.y += ak * w4.y; out.z += ak * w4.z; out.w += ak * w4.w;
        }
        out.x = fmaxf(out.x, 0.f) * di;
        out.y = fmaxf(out.y, 0.f) * di;
        out.z = fmaxf(out.z, 0.f) * di;
        out.w = fmaxf(out.w, 0.f) * di;
        *(float4*)&outslc[aoff + n * 8] = out;
    }
}

// ============ pool: gpool[g][d] = sum_{n in g} agg3[d][n] * dinv[n] (no atomics) ============
__global__ __launch_bounds__(64) void k_pool(const float* __restrict__ agg, // [8][N1][8]
                                             const float* __restrict__ dinv,
                                             const int* __restrict__ gmin,
                                             const int* __restrict__ gmax,
                                             float* __restrict__ gpool,
                                             int* __restrict__ gcnt) {
    int g = blockIdx.x;
    int d = threadIdx.x;
    int off = (d >> 3) * SLICE + (d & 7);
    int lo = gmin[g], hi = gmax[g];
    float s = 0.f;
    for (int n = lo; n < hi; ++n) s += agg[off + n * 8] * dinv[n];
    gpool[g * HIDDEN + d] = s;
    if (d == 0) gcnt[g] = (hi > lo) ? (hi - lo) : 0;
}

// ---------------- final: pooled @ W3 + cnt*b3, @ Wl + bl, softmax ----------------
__global__ __launch_bounds__(256) void k_final(const float* __restrict__ gpool,
                                               const int* __restrict__ gcnt,
                                               const float* __restrict__ W3,
                                               const float* __restrict__ b3,
                                               const float* __restrict__ Wl,
                                               const float* __restrict__ bl,
                                               float* __restrict__ out) {
    int wid = (blockIdx.x * blockDim.x + threadIdx.x) >> 6;
    int lane = threadIdx.x & 63;
    if (wid >= N_GRAPHS) return;
    float pre = gpool[wid * HIDDEN + lane];
    float cnt = (float)gcnt[wid];
    float emb = cnt * b3[lane];
    for (int k = 0; k < HIDDEN; ++k) {
        emb += __shfl(pre, k) * W3[k * HIDDEN + lane];
    }
    float p0 = emb * Wl[lane * 2 + 0];
    float p1 = emb * Wl[lane * 2 + 1];
    for (int d = 32; d > 0; d >>= 1) {
        p0 += __shfl_xor(p0, d);
        p1 += __shfl_xor(p1, d);
    }
    if (lane == 0) {
        float l0 = p0 + bl[0], l1 = p1 + bl[1];
        float m = fmaxf(l0, l1);
        float e0 = __expf(l0 - m), e1 = __expf(l1 - m);
        float inv = 1.f / (e0 + e1);
        out[wid * 2 + 0] = e0 * inv;
        out[wid * 2 + 1] = e1 * inv;
    }
}

extern "C" void kernel_launch(void* const* d_in, const int* in_sizes, int n_in,
                              void* d_out, int out_size, void* d_ws, size_t ws_size,
                              hipStream_t stream) {
    const float* x = (const float*)d_in[0];
    const int* edge = (const int*)d_in[1];
    const int* batch = (const int*)d_in[2];
    const float* W1 = (const float*)d_in[3];
    const float* b1 = (const float*)d_in[4];
    const float* W2 = (const float*)d_in[5];
    const float* b2 = (const float*)d_in[6];
    const float* W3 = (const float*)d_in[7];
    const float* b3 = (const float*)d_in[8];
    const float* Wl = (const float*)d_in[9];
    const float* bl = (const float*)d_in[10];
    float* out = (float*)d_out;

    const int* row = edge;
    const int* col = edge + N_EDGES;

    char* ws = (char*)d_ws;
    size_t off = 0;
    auto alloc = [&](size_t bytes) -> void* {
        void* p = ws + off;
        off = (off + bytes + 255) & ~(size_t)255;
        return p;
    };
    int* deg = (int*)alloc((size_t)N_NODES * 4);
    int* offs = (int*)alloc((size_t)N_NODES * 4);
    int* bsums = (int*)alloc(128 * 4);
    int* cursor = (int*)alloc((size_t)N_NODES * 4);
    float* dinv = (float*)alloc((size_t)N_NODES * 4);
    int* csr_src = (int*)alloc(((size_t)N_EDGES + 256) * 4);
    float* xsAB = (float*)alloc((size_t)2 * SLICE * 4);   // [2][N1][8]
    float* h1slc = (float*)alloc((size_t)8 * SLICE * 4);  // [8][N1][8]; reused as h2slc
    float* aggA = (float*)alloc((size_t)8 * SLICE * 4);   // [8][N1][8]; agg1/agg2/agg3
    float* gpool = (float*)alloc((size_t)N_GRAPHS * HIDDEN * 4);
    int* gmin = (int*)alloc((size_t)N_GRAPHS * 4);
    int* gmax = (int*)alloc((size_t)N_GRAPHS * 4);
    int* gcnt = (int*)alloc((size_t)N_GRAPHS * 4);

    hipMemsetAsync(deg, 0, (size_t)N_NODES * 4, stream);
    hipMemsetAsync(cursor, 0, (size_t)N_NODES * 4, stream);
    hipMemsetAsync(gmin, 0x7f, (size_t)N_GRAPHS * 4, stream);  // 0x7f7f7f7f > N_NODES
    hipMemsetAsync(gmax, 0, (size_t)N_GRAPHS * 4, stream);

    const int EB = (N_EDGES + 255) / 256;
    const int NB1024 = (N_NODES + 1023) / 1024;

    k_deg<<<EB, 256, 0, stream>>>(col, deg);
    k_scan_block<<<NB1024, 1024, 0, stream>>>(deg, offs, bsums);
    k_scan_top<<<1, 128, 0, stream>>>(bsums, NB1024);
    k_scan_add<<<NB1024, 1024, 0, stream>>>(offs, bsums);
    k_dinv<<<(N_NODES + 255) / 256, 256, 0, stream>>>(deg, dinv);

    const int NCHUNKS = (N_EDGES + CHUNK_EDGES - 1) / CHUNK_EDGES;
    k_fill<<<NCHUNKS * NRANGES, 256, 0, stream>>>(row, col, offs, cursor, csr_src);
    k_prex<<<(N1 * 16 + 255) / 256, 256, 0, stream>>>(x, dinv, xsAB);
    k_zerosink<<<1, 64, 0, stream>>>(h1slc);
    k_bounds<<<(N_NODES + 255) / 256, 256, 0, stream>>>(batch, gmin, gmax);

    // layer 1: 2 sliced gather passes over x, then dense W1
    k_gather8<<<2 * GNB, 256, 0, stream>>>(xsAB, offs, deg, csr_src, aggA);
    k_dense1<<<2048, 256, 0, stream>>>(aggA, dinv, W1, b1, h1slc);
    // layer 2: 8 sliced gather passes over h1, then dense W2 (h2 written in place of h1)
    k_gather8<<<8 * GNB, 256, 0, stream>>>(h1slc, offs, deg, csr_src, aggA);
    k_dense2<<<2048, 256, 0, stream>>>(aggA, dinv, W2, b2, h1slc);
    // layer 3: 8 sliced gather passes over h2; pool without atomics (W3 commutes past pool)
    k_gather8<<<8 * GNB, 256, 0, stream>>>(h1slc, offs, deg, csr_src, aggA);
    k_pool<<<N_GRAPHS, 64, 0, stream>>>(aggA, dinv, gmin, gmax, gpool, gcnt);
    k_final<<<(N_GRAPHS * 64 + 255) / 256, 256, 0, stream>>>(gpool, gcnt, W3, b3, Wl, bl, out);
}